// Round 16
// baseline (522.902 us; speedup 1.0000x reference)
//
#include <hip/hip_runtime.h>
#include <stdint.h>
#include <math.h>

typedef unsigned short u16;
typedef short s16x8 __attribute__((ext_vector_type(8)));
typedef float f32x4 __attribute__((ext_vector_type(4)));
typedef u16 u16x4 __attribute__((ext_vector_type(4)));

#define FDIM 512
#define F2 1024
#define BATCH 16384
#define NST 6
#define KDIM 1024
#define NT 32   // K-tiles of 32 (gemm2 core, unchanged)
#define NKT 16  // K-tiles of 64 (gemm1 8-phase core)

// round-to-nearest-even fp32 -> bf16 bits
__device__ __forceinline__ u16 f2bf(float f) {
  uint32_t u = __float_as_uint(f);
  u += 0x7FFFu + ((u >> 16) & 1u);
  return (u16)(u >> 16);
}
__device__ __forceinline__ float bf2f(u16 b) {
  return __uint_as_float((uint32_t)b << 16);
}

// fast activations: v_exp_f32 + v_rcp_f32 (verified round 7)
#define LOG2E 1.44269504f
__device__ __forceinline__ float fast_sigmoid(float v) {
  float e = __builtin_amdgcn_exp2f(-v * LOG2E);
  return __builtin_amdgcn_rcpf(1.0f + e);
}
__device__ __forceinline__ float fast_tanh(float v) {
  float e = __builtin_amdgcn_exp2f(v * (2.0f * LOG2E));
  return 1.0f - 2.0f * __builtin_amdgcn_rcpf(1.0f + e);
}

__device__ __forceinline__ void ld_lds16(u16* lds, const u16* g) {
  __builtin_amdgcn_global_load_lds(
      (const __attribute__((address_space(1))) uint32_t*)g,
      (__attribute__((address_space(3))) uint32_t*)lds, 16, 0, 0);
}

// ---------------- entmax 1.5, fully parallel (512 thr / row) ----------------
__global__ __launch_bounds__(512) void entmax_kernel(const float* __restrict__ masks,
                                                     float* __restrict__ fm) {
  __shared__ float sx[FDIM];
  __shared__ float ssort[FDIM];
  __shared__ float stau[FDIM];
  __shared__ float2 sc[2][FDIM];
  const int d = blockIdx.x;
  const int j = threadIdx.x;
  float v = masks[d * FDIM + j];

  stau[j] = v;
  __syncthreads();
  for (int s = 256; s > 0; s >>= 1) {
    if (j < s) stau[j] = fmaxf(stau[j], stau[j + s]);
    __syncthreads();
  }
  float mx = stau[0];
  __syncthreads();

  float xx = (v - mx) * 0.5f;
  sx[j] = xx;
  __syncthreads();

  int r = 0;
  const float4* sx4 = (const float4*)sx;
#pragma unroll 4
  for (int i4 = 0; i4 < FDIM / 4; i4++) {
    float4 q = sx4[i4];
    int i = i4 << 2;
    r += (q.x > xx) || (q.x == xx && (i + 0) < j);
    r += (q.y > xx) || (q.y == xx && (i + 1) < j);
    r += (q.z > xx) || (q.z == xx && (i + 2) < j);
    r += (q.w > xx) || (q.w == xx && (i + 3) < j);
  }
  ssort[r] = xx;
  __syncthreads();
  float xs = ssort[j];

  sc[0][j] = make_float2(xs, xs * xs);
  __syncthreads();
  int pp = 0;
  for (int off = 1; off < FDIM; off <<= 1) {
    float2 t = sc[pp][j];
    if (j >= off) {
      float2 u = sc[pp][j - off];
      t.x += u.x;
      t.y += u.y;
    }
    sc[pp ^ 1][j] = t;
    __syncthreads();
    pp ^= 1;
  }
  float2 cs = sc[pp][j];

  float rho = (float)(j + 1);
  float mean = cs.x / rho;
  float msq = cs.y / rho;
  float ss = rho * (msq - mean * mean);
  float delta = (1.f - ss) / rho;
  if (delta < 0.f) delta = 0.f;
  float tau = mean - sqrtf(delta);
  stau[j] = tau;
  int cnt = __syncthreads_count(tau <= xs);
  float tstar = stau[cnt - 1];
  float c = fmaxf(xx - tstar, 0.f);
  fm[d * FDIM + j] = c * c;
}

// ---------------- W1 -> bf16, fm folded into first 512 cols -----------------
__global__ __launch_bounds__(256) void cvt_w1_kernel(const float* __restrict__ src,
                                                     const float* __restrict__ fm,
                                                     u16* __restrict__ dst) {
  int t = blockIdx.x * 256 + threadIdx.x;
  int k = (t & 255) << 2;
  int dn = t >> 8;
  int d = dn >> 10;
  float4 v = *(const float4*)(src + (size_t)t * 4);
  if (k < FDIM) {
    float4 s = *(const float4*)(fm + (size_t)d * FDIM + k);
    v.x *= s.x; v.y *= s.y; v.z *= s.z; v.w *= s.w;
  }
  u16x4 o = {f2bf(v.x), f2bf(v.y), f2bf(v.z), f2bf(v.w)};
  *(u16x4*)(dst + (size_t)t * 4) = o;
}

// --------- merged prep: W2 -> bf16  AND  A1/A2 x-fill (one launch) ----------
#define N4_W2 (NST * FDIM * F2 / 4)
__global__ __launch_bounds__(256) void prep_kernel(const float* __restrict__ W2f,
                                                   u16* __restrict__ W2b,
                                                   const float* __restrict__ x,
                                                   u16* __restrict__ A1,
                                                   u16* __restrict__ A2) {
  int t = blockIdx.x * 256 + threadIdx.x;
  if (t < N4_W2) {
    float4 v = *(const float4*)(W2f + (size_t)t * 4);
    u16x4 o = {f2bf(v.x), f2bf(v.y), f2bf(v.z), f2bf(v.w)};
    *(u16x4*)(W2b + (size_t)t * 4) = o;
  } else {
    int u = t - N4_W2;
    int m = u >> 7;
    int c = (u & 127) << 2;
    float4 xv = *(const float4*)(x + (size_t)m * FDIM + c);
    u16x4 o = {f2bf(xv.x), f2bf(xv.y), f2bf(xv.z), f2bf(xv.w)};
    *(u16x4*)(A1 + (size_t)m * F2 + c) = o;
    *(u16x4*)(A1 + (size_t)m * F2 + FDIM + c) = o;  // h = x at stage 0 (bf16)
    *(u16x4*)(A2 + (size_t)m * F2 + FDIM + c) = o;
  }
}

// ============ gemm1: 256x128 / BK=64 / 3-slot ring / 4-phase-per-kt =========
// 512 thr = 8 waves (4M x 2N), wave C = 64x64 = 4mf x 4nf frags (16x16x32).
// LDS slot (48KB = 24576 u16): A-h0 [0,8192), A-h1 [8192,16384), B [16384,24576).
// Per kt: 4 quadrant phases (gray (mh,nh): 00,01,11,10), 8 MFMA each; each
// phase stages one 16KB unit (2 global_load_lds) of kt j+2 -> slot (j+2)%3
// which held kt j-1 (reads closed by kt j-1 q3 end-barrier -> race-free).
// Guard kt j+1 at q3: vmcnt(6) (kt j+2's 6 loads stay in flight, lead 5-7
// phases) + barrier; tail j=14 -> vmcnt(0). Swizzle for 128B rows: chunk
// c' = c ^ (row&7) both-sides; uniform banks (8 lanes/16B col).
__global__ __launch_bounds__(512, 2) void gemm1_kernel(const u16* __restrict__ A1,
                                                       const u16* __restrict__ W1,
                                                       const float* __restrict__ b1,
                                                       _Float16* __restrict__ zbuf,
                                                       u16* __restrict__ A2) {
  __shared__ u16 smem[73728];  // 144 KB: 3 x 24576 u16 slots
  const int bx = blockIdx.x;
  const int wg = (bx & 7) * 64 + (bx >> 3);  // XCD swizzle, 512 wgs
  const int m0 = (wg >> 3) << 8;             // 64 m-blocks of 256
  const int n0 = (wg & 7) << 7;              // 8 n-blocks of 128

  const int tid = threadIdx.x;
  const int lane = tid & 63;
  const int wid = tid >> 6;
  const int wm = wid >> 1;  // 0..3 -> rows wm*64
  const int wn = wid & 1;   // 0..1 -> cols wn*64
  const int l15 = lane & 15;
  const int kg = lane >> 4;  // 0..3

  // staging source (pre-swizzled global col-chunk)
  const int csrc = ((tid & 7) ^ ((tid >> 3) & 7)) << 3;  // u16 units
  const u16* gA = A1 + (size_t)(m0 + (tid >> 3)) * KDIM + csrc;
  const u16* gB = W1 + (size_t)(n0 + (tid >> 3)) * KDIM + csrc;
  const int ldst = tid * 8;  // per-thread LDS chunk (u16)

  // frag read bases (swizzled chunk per k-substep)
  int cA0 = ((0 * 4 + kg) ^ (l15 & 7)) << 3;
  int cA1 = ((1 * 4 + kg) ^ (l15 & 7)) << 3;
  const int rowbaseA = (wm >> 1) * 8192 + ((wm & 1) * 64 + l15) * 64;
  const int rowbaseB = 16384 + (wn * 64 + l15) * 64;

  f32x4 acc[4][4];
#pragma unroll
  for (int i = 0; i < 4; i++)
#pragma unroll
    for (int j = 0; j < 4; j++) acc[i][j] = (f32x4){0.f, 0.f, 0.f, 0.f};

  // ---- prologue: stage kt0 -> slot0, kt1 -> slot1 (6 units, 12 loads) ----
#pragma unroll
  for (int jj = 0; jj < 2; jj++) {
    u16* sb = smem + jj * 24576;
    const u16* ga = gA + jj * 64;
    const u16* gb = gB + jj * 64;
    ld_lds16(sb + ldst, ga);                                   // A-h0 rows 0-63
    ld_lds16(sb + 4096 + ldst, ga + (size_t)64 * KDIM);        // A-h0 rows 64-127
    ld_lds16(sb + 8192 + ldst, ga + (size_t)128 * KDIM);       // A-h1 rows 0-63
    ld_lds16(sb + 12288 + ldst, ga + (size_t)192 * KDIM);      // A-h1 rows 64-127
    ld_lds16(sb + 16384 + ldst, gb);                           // B rows 0-63
    ld_lds16(sb + 20480 + ldst, gb + (size_t)64 * KDIM);       // B rows 64-127
  }
  asm volatile("s_waitcnt vmcnt(6)" ::: "memory");  // kt0 landed; kt1 in flight
  __builtin_amdgcn_s_barrier();
  __builtin_amdgcn_sched_barrier(0);

  s16x8 afq[2][2], bfq[2][2];  // current quadrant operands (persist across q)

  int slot = 0, sslot = 2;
  for (int j = 0; j < NKT; j++) {
    const u16* rb = smem + slot * 24576;
    u16* sb = smem + sslot * 24576;
    const int js = j + 2;
    const u16* ga = gA + js * 64;
    const u16* gb = gB + js * 64;
    const bool do_stage = (js < NKT);

#pragma unroll
    for (int q = 0; q < 4; q++) {
      const int mh = (q >> 1);               // 0,0,1,1
      const int nh = (q == 1 || q == 2);     // 0,1,1,0
      // ---- ds reads for this quadrant ----
      if (q == 0 || q == 2) {
#pragma unroll
        for (int i = 0; i < 2; i++) {
          afq[i][0] = *(const s16x8*)(rb + rowbaseA + (mh * 2 + i) * 1024 + cA0);
          afq[i][1] = *(const s16x8*)(rb + rowbaseA + (mh * 2 + i) * 1024 + cA1);
        }
      }
      if (q != 2) {
#pragma unroll
        for (int n = 0; n < 2; n++) {
          bfq[n][0] = *(const s16x8*)(rb + rowbaseB + (nh * 2 + n) * 1024 + cA0);
          bfq[n][1] = *(const s16x8*)(rb + rowbaseB + (nh * 2 + n) * 1024 + cA1);
        }
      }
      // ---- stage unit q of kt j+2 (targets slot of dead kt j-1) ----
      if (do_stage) {
        if (q == 0) {
          ld_lds16(sb + ldst, ga);
          ld_lds16(sb + 4096 + ldst, ga + (size_t)64 * KDIM);
        } else if (q == 1) {
          ld_lds16(sb + 8192 + ldst, ga + (size_t)128 * KDIM);
          ld_lds16(sb + 12288 + ldst, ga + (size_t)192 * KDIM);
        } else if (q == 2) {
          ld_lds16(sb + 16384 + ldst, gb);
          ld_lds16(sb + 20480 + ldst, gb + (size_t)64 * KDIM);
        }
      }
      __builtin_amdgcn_s_barrier();
      asm volatile("s_waitcnt lgkmcnt(0)" ::: "memory");
      __builtin_amdgcn_sched_barrier(0);
      __builtin_amdgcn_s_setprio(1);
#pragma unroll
      for (int s = 0; s < 2; s++)
#pragma unroll
        for (int i = 0; i < 2; i++)
#pragma unroll
          for (int n = 0; n < 2; n++)
            acc[mh * 2 + i][nh * 2 + n] = __builtin_amdgcn_mfma_f32_16x16x32_bf16(
                afq[i][s], bfq[n][s], acc[mh * 2 + i][nh * 2 + n], 0, 0, 0);
      __builtin_amdgcn_s_setprio(0);
      __builtin_amdgcn_sched_barrier(0);
      if (q == 3) {  // guard kt j+1 before its reads next iteration
        if (j <= 13) {
          asm volatile("s_waitcnt vmcnt(6)" ::: "memory");
        } else if (j == 14) {
          asm volatile("s_waitcnt vmcnt(0)" ::: "memory");
        }
      }
      __builtin_amdgcn_s_barrier();
      __builtin_amdgcn_sched_barrier(0);
    }
    slot = (slot == 2) ? 0 : slot + 1;
    sslot = (sslot == 2) ? 0 : sslot + 1;
  }

  // ---- fused epilogue ----
  const int fcol = l15;
  const int frow = kg << 2;
  if (n0 < FDIM) {  // z-half
#pragma unroll
    for (int f = 0; f < 4; f++)
#pragma unroll
      for (int g = 0; g < 4; g++)
#pragma unroll
        for (int r = 0; r < 4; r++) {
          int gm = m0 + wm * 64 + f * 16 + frow + r;
          int gn = n0 + wn * 64 + g * 16 + fcol;
          float v = acc[f][g][r] + b1[gn];
          zbuf[(size_t)gm * FDIM + gn] = (_Float16)fast_sigmoid(v);
        }
  } else {  // r-half -> A2 left = bf16(r*h)
#pragma unroll
    for (int f = 0; f < 4; f++)
#pragma unroll
      for (int g = 0; g < 4; g++)
#pragma unroll
        for (int r = 0; r < 4; r++) {
          int gm = m0 + wm * 64 + f * 16 + frow + r;
          int gn = n0 + wn * 64 + g * 16 + fcol;
          float v = acc[f][g][r] + b1[gn];
          float s = fast_sigmoid(v);
          int c = gn - FDIM;
          float h = bf2f(A1[(size_t)gm * F2 + FDIM + c]);
          A2[(size_t)gm * F2 + c] = f2bf(s * h);
        }
  }
}

// ====================== 128x256 single-barrier GEMM core =====================
// (r12-verified; unchanged) per wave 64x64 = acc[4][4]. Ring-4 x 24KB,
// lead-3, vmcnt(6/3/0), 16 MFMA + 1 barrier per K-tile.
__device__ __forceinline__ void gemm_core4(const u16* __restrict__ Ag,
                                           const u16* __restrict__ Bg,
                                           int m0, int n0, u16* smem,
                                           f32x4 acc[4][4]) {
  const int tid = threadIdx.x;
  const int lane = tid & 63;
  const int wid = tid >> 6;
  const int wm = wid >> 2;
  const int wn = wid & 3;

  const int rs = tid >> 2;
  const int colsw = ((tid & 3) ^ ((rs >> 1) & 3)) << 3;
  const u16* gA0 = Ag + (size_t)(m0 + rs) * KDIM + colsw;
  const u16* gB0 = Bg + (size_t)(n0 + rs) * KDIM + colsw;
  const u16* gB1 = gB0 + (size_t)128 * KDIM;
  const int lds_u = tid * 8;

  const int fcs = ((lane >> 4) ^ ((lane >> 1) & 3)) << 3;
  const int aoff = (wm * 64 + (lane & 15)) * 32 + fcs;
  const int boff = (wn * 64 + (lane & 15)) * 32 + fcs;

#pragma unroll
  for (int i = 0; i < 4; i++)
#pragma unroll
    for (int j = 0; j < 4; j++) acc[i][j] = (f32x4){0.f, 0.f, 0.f, 0.f};

#pragma unroll
  for (int kt = 0; kt < 3; kt++) {
    u16* rb = smem + kt * 12288;
    ld_lds16(rb + lds_u, gA0 + kt * 32);
    ld_lds16(rb + 4096 + lds_u, gB0 + kt * 32);
    ld_lds16(rb + 8192 + lds_u, gB1 + kt * 32);
  }
  asm volatile("s_waitcnt vmcnt(6)" ::: "memory");
  __builtin_amdgcn_s_barrier();
  __builtin_amdgcn_sched_barrier(0);

  for (int t = 0; t < NT; t++) {
    const u16* rb = smem + (t & 3) * 12288;
    u16* sb = smem + ((t + 3) & 3) * 12288;
    if (t + 3 < NT) {
      ld_lds16(sb + lds_u, gA0 + (t + 3) * 32);
      ld_lds16(sb + 4096 + lds_u, gB0 + (t + 3) * 32);
      ld_lds16(sb + 8192 + lds_u, gB1 + (t + 3) * 32);
    }
    s16x8 af[4], bfr[4];
#pragma unroll
    for (int f = 0; f < 4; f++)
      af[f] = *(const s16x8*)(rb + aoff + f * 512);
#pragma unroll
    for (int g = 0; g < 4; g++)
      bfr[g] = *(const s16x8*)(rb + 4096 + boff + g * 512);
    if (t < NT - 3) {
      asm volatile("s_waitcnt vmcnt(6)" ::: "memory");
    } else if (t == NT - 3) {
      asm volatile("s_waitcnt vmcnt(3)" ::: "memory");
    } else if (t == NT - 2) {
      asm volatile("s_waitcnt vmcnt(0)" ::: "memory");
    }
    __builtin_amdgcn_s_setprio(1);
#pragma unroll
    for (int f = 0; f < 4; f++)
#pragma unroll
      for (int g = 0; g < 4; g++)
        acc[f][g] = __builtin_amdgcn_mfma_f32_16x16x32_bf16(af[f], bfr[g], acc[f][g], 0, 0, 0);
    __builtin_amdgcn_s_setprio(0);
    __builtin_amdgcn_sched_barrier(0);
    __builtin_amdgcn_s_barrier();
    __builtin_amdgcn_sched_barrier(0);
  }
}

// ---------------- GEMM2: h_out = tanh(A2 @ W2^T + b2); gated update ---------
__global__ __launch_bounds__(512, 2) void gemm2_kernel(const u16* __restrict__ A2,
                                                       const u16* __restrict__ W2,
                                                       const float* __restrict__ b2,
                                                       const _Float16* __restrict__ zbuf,
                                                       u16* __restrict__ A1,
                                                       float* __restrict__ out,
                                                       int last) {
  __shared__ u16 smem[49152];
  const int bx = blockIdx.x;
  const int wg = (bx & 7) * 32 + (bx >> 3);  // XCD swizzle, 256 wgs
  const int m0 = (wg >> 1) << 7;             // BM=128
  const int n0 = (wg & 1) << 8;              // BN=256
  f32x4 acc[4][4];
  gemm_core4(A2, W2, m0, n0, smem, acc);

  const int lane = threadIdx.x & 63;
  const int wid = threadIdx.x >> 6;
  const int wm = wid >> 2;
  const int wn = wid & 3;
  const int fcol = lane & 15;
  const int frow = (lane >> 4) << 2;

#pragma unroll
  for (int f = 0; f < 4; f++)
#pragma unroll
    for (int g = 0; g < 4; g++)
#pragma unroll
      for (int r = 0; r < 4; r++) {
        int gm = m0 + wm * 64 + f * 16 + frow + r;
        int gn = n0 + wn * 64 + g * 16 + fcol;
        float v = acc[f][g][r] + b2[gn];
        float ho = fast_tanh(v);
        size_t idx = (size_t)gm * FDIM + gn;
        float z = (float)zbuf[idx];
        float hv = bf2f(A1[(size_t)gm * F2 + FDIM + gn]);
        float hn = (1.0f - z) * hv + z * ho;
        if (last)
          out[idx] = hn;
        else
          A1[(size_t)gm * F2 + FDIM + gn] = f2bf(hn);
      }
}

extern "C" void kernel_launch(void* const* d_in, const int* in_sizes, int n_in,
                              void* d_out, int out_size, void* d_ws, size_t ws_size,
                              hipStream_t stream) {
  (void)in_sizes; (void)n_in; (void)out_size; (void)ws_size;
  const float* x = (const float*)d_in[0];
  const float* masks = (const float*)d_in[1];
  const float* W1f = (const float*)d_in[2];
  const float* b1 = (const float*)d_in[3];
  const float* W2f = (const float*)d_in[4];
  const float* b2 = (const float*)d_in[5];

  char* ws = (char*)d_ws;
  float* fm = (float*)ws;       ws += (size_t)NST * FDIM * 4;
  u16* W1b = (u16*)ws;          ws += (size_t)NST * F2 * F2 * 2;
  u16* W2b = (u16*)ws;          ws += (size_t)NST * FDIM * F2 * 2;
  u16* A1 = (u16*)ws;           ws += (size_t)BATCH * F2 * 2;
  u16* A2 = (u16*)ws;           ws += (size_t)BATCH * F2 * 2;
  _Float16* zbuf = (_Float16*)ws; ws += (size_t)BATCH * FDIM * 2;
  float* out = (float*)d_out;

  entmax_kernel<<<NST, 512, 0, stream>>>(masks, fm);
  cvt_w1_kernel<<<NST * F2 * F2 / 4 / 256, 256, 0, stream>>>(W1f, fm, W1b);
  {
    int total = N4_W2 + BATCH * 128;  // W2 cvt + x-fill, one launch
    prep_kernel<<<(total + 255) / 256, 256, 0, stream>>>(W2f, W2b, x, A1, A2);
  }

  for (int d = 0; d < NST; d++) {
    gemm1_kernel<<<(BATCH / 256) * (F2 / 128), 512, 0, stream>>>(
        A1, W1b + (size_t)d * F2 * F2, b1 + d * F2, zbuf, A2);
    gemm2_kernel<<<(BATCH / 128) * (FDIM / 256), 512, 0, stream>>>(
        A2, W2b + (size_t)d * FDIM * F2, b2 + d * FDIM, zbuf,
        A1, out, d == NST - 1);
  }
}

// Round 17
// 493.959 us; speedup vs baseline: 1.0586x; 1.0586x over previous
//
#include <hip/hip_runtime.h>
#include <stdint.h>
#include <math.h>

typedef unsigned short u16;
typedef short s16x8 __attribute__((ext_vector_type(8)));
typedef float f32x4 __attribute__((ext_vector_type(4)));
typedef u16 u16x4 __attribute__((ext_vector_type(4)));

#define FDIM 512
#define F2 1024
#define BATCH 16384
#define NST 6
#define KDIM 1024
#define NT 32  // K-tiles of 32

// round-to-nearest-even fp32 -> bf16 bits
__device__ __forceinline__ u16 f2bf(float f) {
  uint32_t u = __float_as_uint(f);
  u += 0x7FFFu + ((u >> 16) & 1u);
  return (u16)(u >> 16);
}
__device__ __forceinline__ float bf2f(u16 b) {
  return __uint_as_float((uint32_t)b << 16);
}

// fast activations: v_exp_f32 + v_rcp_f32 (verified round 7: -65us, exact)
#define LOG2E 1.44269504f
__device__ __forceinline__ float fast_sigmoid(float v) {
  float e = __builtin_amdgcn_exp2f(-v * LOG2E);
  return __builtin_amdgcn_rcpf(1.0f + e);
}
__device__ __forceinline__ float fast_tanh(float v) {
  float e = __builtin_amdgcn_exp2f(v * (2.0f * LOG2E));
  return 1.0f - 2.0f * __builtin_amdgcn_rcpf(1.0f + e);
}

__device__ __forceinline__ void ld_lds16(u16* lds, const u16* g) {
  __builtin_amdgcn_global_load_lds(
      (const __attribute__((address_space(1))) uint32_t*)g,
      (__attribute__((address_space(3))) uint32_t*)lds, 16, 0, 0);
}

// ---------------- entmax 1.5, fully parallel (512 thr / row) ----------------
__global__ __launch_bounds__(512) void entmax_kernel(const float* __restrict__ masks,
                                                     float* __restrict__ fm) {
  __shared__ float sx[FDIM];
  __shared__ float ssort[FDIM];
  __shared__ float stau[FDIM];
  __shared__ float2 sc[2][FDIM];
  const int d = blockIdx.x;
  const int j = threadIdx.x;
  float v = masks[d * FDIM + j];

  stau[j] = v;
  __syncthreads();
  for (int s = 256; s > 0; s >>= 1) {
    if (j < s) stau[j] = fmaxf(stau[j], stau[j + s]);
    __syncthreads();
  }
  float mx = stau[0];
  __syncthreads();

  float xx = (v - mx) * 0.5f;
  sx[j] = xx;
  __syncthreads();

  int r = 0;
  const float4* sx4 = (const float4*)sx;
#pragma unroll 4
  for (int i4 = 0; i4 < FDIM / 4; i4++) {
    float4 q = sx4[i4];
    int i = i4 << 2;
    r += (q.x > xx) || (q.x == xx && (i + 0) < j);
    r += (q.y > xx) || (q.y == xx && (i + 1) < j);
    r += (q.z > xx) || (q.z == xx && (i + 2) < j);
    r += (q.w > xx) || (q.w == xx && (i + 3) < j);
  }
  ssort[r] = xx;
  __syncthreads();
  float xs = ssort[j];

  // inclusive Hillis-Steele scan of (xs, xs^2)
  sc[0][j] = make_float2(xs, xs * xs);
  __syncthreads();
  int pp = 0;
  for (int off = 1; off < FDIM; off <<= 1) {
    float2 t = sc[pp][j];
    if (j >= off) {
      float2 u = sc[pp][j - off];
      t.x += u.x;
      t.y += u.y;
    }
    sc[pp ^ 1][j] = t;
    __syncthreads();
    pp ^= 1;
  }
  float2 cs = sc[pp][j];

  float rho = (float)(j + 1);
  float mean = cs.x / rho;
  float msq = cs.y / rho;
  float ss = rho * (msq - mean * mean);
  float delta = (1.f - ss) / rho;
  if (delta < 0.f) delta = 0.f;
  float tau = mean - sqrtf(delta);
  stau[j] = tau;
  int cnt = __syncthreads_count(tau <= xs);
  float tstar = stau[cnt - 1];
  float c = fmaxf(xx - tstar, 0.f);
  fm[d * FDIM + j] = c * c;
}

// ---------------- W1 -> bf16, fm folded into first 512 cols -----------------
__global__ __launch_bounds__(256) void cvt_w1_kernel(const float* __restrict__ src,
                                                     const float* __restrict__ fm,
                                                     u16* __restrict__ dst) {
  int t = blockIdx.x * 256 + threadIdx.x;
  int k = (t & 255) << 2;
  int dn = t >> 8;
  int d = dn >> 10;
  float4 v = *(const float4*)(src + (size_t)t * 4);
  if (k < FDIM) {
    float4 s = *(const float4*)(fm + (size_t)d * FDIM + k);
    v.x *= s.x; v.y *= s.y; v.z *= s.z; v.w *= s.w;
  }
  u16x4 o = {f2bf(v.x), f2bf(v.y), f2bf(v.z), f2bf(v.w)};
  *(u16x4*)(dst + (size_t)t * 4) = o;
}

// --------- merged prep: W2 -> bf16  AND  A1/A2 x-fill (one launch) ----------
#define N4_W2 (NST * FDIM * F2 / 4)
__global__ __launch_bounds__(256) void prep_kernel(const float* __restrict__ W2f,
                                                   u16* __restrict__ W2b,
                                                   const float* __restrict__ x,
                                                   u16* __restrict__ A1,
                                                   u16* __restrict__ A2) {
  int t = blockIdx.x * 256 + threadIdx.x;
  if (t < N4_W2) {
    float4 v = *(const float4*)(W2f + (size_t)t * 4);
    u16x4 o = {f2bf(v.x), f2bf(v.y), f2bf(v.z), f2bf(v.w)};
    *(u16x4*)(W2b + (size_t)t * 4) = o;
  } else {
    int u = t - N4_W2;
    int m = u >> 7;
    int c = (u & 127) << 2;
    float4 xv = *(const float4*)(x + (size_t)m * FDIM + c);
    u16x4 o = {f2bf(xv.x), f2bf(xv.y), f2bf(xv.z), f2bf(xv.w)};
    *(u16x4*)(A1 + (size_t)m * F2 + c) = o;
    *(u16x4*)(A1 + (size_t)m * F2 + FDIM + c) = o;  // h = x at stage 0 (bf16)
    *(u16x4*)(A2 + (size_t)m * F2 + FDIM + c) = o;
  }
}

// ====================== 256x256 single-barrier GEMM core =====================
// (r8/r12-verified best) 512 thr = 8 waves (2M x 4N); per wave 128x64 =
// acc[8][4]. Ring-4 LDS, lead-3 staging, vmcnt(8) steady / 4 / 0 tail. ONE
// barrier per K-tile; stage at t targets buf (t+3)&3 == (t-1)&3 (reads
// drained before the end-of-(t-1) barrier). Swizzle cg = kg ^ ((row>>1)&3):
// 0 conflicts (verified r6; 32x32 variant re-conflicts, r14 — keep 16x16).
__device__ __forceinline__ void gemm_core8(const u16* __restrict__ Ag,
                                           const u16* __restrict__ Bg,
                                           int m0, int n0, u16* smem,
                                           f32x4 acc[8][4]) {
  const int tid = threadIdx.x;
  const int lane = tid & 63;
  const int wid = tid >> 6;
  const int wm = wid >> 2;  // 0..1
  const int wn = wid & 3;   // 0..3

  const int rs = tid >> 2;                               // 0..127
  const int colsw = ((tid & 3) ^ ((rs >> 1) & 3)) << 3;  // pre-swizzled global col
  const u16* gA0 = Ag + (size_t)(m0 + rs) * KDIM + colsw;
  const u16* gA1 = gA0 + (size_t)128 * KDIM;
  const u16* gB0 = Bg + (size_t)(n0 + rs) * KDIM + colsw;
  const u16* gB1 = gB0 + (size_t)128 * KDIM;
  const int lds_u = tid * 8;

  const int fcs = ((lane >> 4) ^ ((lane >> 1) & 3)) << 3;  // swizzled frag col
  const int aoff = (wm * 128 + (lane & 15)) * 32 + fcs;
  const int boff = (wn * 64 + (lane & 15)) * 32 + fcs;

#pragma unroll
  for (int i = 0; i < 8; i++)
#pragma unroll
    for (int j = 0; j < 4; j++) acc[i][j] = (f32x4){0.f, 0.f, 0.f, 0.f};

#pragma unroll
  for (int kt = 0; kt < 3; kt++) {
    u16* rb = smem + kt * 16384;
    ld_lds16(rb + lds_u, gA0 + kt * 32);
    ld_lds16(rb + 4096 + lds_u, gA1 + kt * 32);
    ld_lds16(rb + 8192 + lds_u, gB0 + kt * 32);
    ld_lds16(rb + 12288 + lds_u, gB1 + kt * 32);
  }
  asm volatile("s_waitcnt vmcnt(8)" ::: "memory");  // K-tile 0 landed
  __builtin_amdgcn_s_barrier();
  __builtin_amdgcn_sched_barrier(0);

  for (int t = 0; t < NT; t++) {
    const u16* rb = smem + (t & 3) * 16384;
    u16* sb = smem + ((t + 3) & 3) * 16384;
    // issue next-tile stage first (flies during ds_reads + MFMA)
    if (t + 3 < NT) {
      ld_lds16(sb + lds_u, gA0 + (t + 3) * 32);
      ld_lds16(sb + 4096 + lds_u, gA1 + (t + 3) * 32);
      ld_lds16(sb + 8192 + lds_u, gB0 + (t + 3) * 32);
      ld_lds16(sb + 12288 + lds_u, gB1 + (t + 3) * 32);
    }
    // all 12 frags of this tile
    s16x8 af[8], bfr[4];
#pragma unroll
    for (int f = 0; f < 8; f++)
      af[f] = *(const s16x8*)(rb + aoff + f * 512);
#pragma unroll
    for (int g = 0; g < 4; g++)
      bfr[g] = *(const s16x8*)(rb + 8192 + boff + g * 512);
    // own buf[t+1] loads landed (8 = t+2,t+3 still in flight)
    if (t < NT - 3) {
      asm volatile("s_waitcnt vmcnt(8)" ::: "memory");
    } else if (t == NT - 3) {
      asm volatile("s_waitcnt vmcnt(4)" ::: "memory");
    } else if (t == NT - 2) {
      asm volatile("s_waitcnt vmcnt(0)" ::: "memory");
    }
    __builtin_amdgcn_s_setprio(1);
#pragma unroll
    for (int f = 0; f < 8; f++)
#pragma unroll
      for (int g = 0; g < 4; g++)
        acc[f][g] = __builtin_amdgcn_mfma_f32_16x16x32_bf16(af[f], bfr[g], acc[f][g], 0, 0, 0);
    __builtin_amdgcn_s_setprio(0);
    __builtin_amdgcn_sched_barrier(0);
    __builtin_amdgcn_s_barrier();  // single rendezvous per K-tile
    __builtin_amdgcn_sched_barrier(0);
  }
}

// ====================== 128x256 single-barrier GEMM core =====================
// per wave 64x64 = acc[4][4]. Ring-4 x 24KB, lead-3, vmcnt(6/3/0),
// 16 MFMA + 1 barrier per K-tile (same safety argument as core8).
__device__ __forceinline__ void gemm_core4(const u16* __restrict__ Ag,
                                           const u16* __restrict__ Bg,
                                           int m0, int n0, u16* smem,
                                           f32x4 acc[4][4]) {
  const int tid = threadIdx.x;
  const int lane = tid & 63;
  const int wid = tid >> 6;
  const int wm = wid >> 2;
  const int wn = wid & 3;

  const int rs = tid >> 2;
  const int colsw = ((tid & 3) ^ ((rs >> 1) & 3)) << 3;
  const u16* gA0 = Ag + (size_t)(m0 + rs) * KDIM + colsw;
  const u16* gB0 = Bg + (size_t)(n0 + rs) * KDIM + colsw;
  const u16* gB1 = gB0 + (size_t)128 * KDIM;
  const int lds_u = tid * 8;

  const int fcs = ((lane >> 4) ^ ((lane >> 1) & 3)) << 3;
  const int aoff = (wm * 64 + (lane & 15)) * 32 + fcs;
  const int boff = (wn * 64 + (lane & 15)) * 32 + fcs;

#pragma unroll
  for (int i = 0; i < 4; i++)
#pragma unroll
    for (int j = 0; j < 4; j++) acc[i][j] = (f32x4){0.f, 0.f, 0.f, 0.f};

#pragma unroll
  for (int kt = 0; kt < 3; kt++) {
    u16* rb = smem + kt * 12288;
    ld_lds16(rb + lds_u, gA0 + kt * 32);
    ld_lds16(rb + 4096 + lds_u, gB0 + kt * 32);
    ld_lds16(rb + 8192 + lds_u, gB1 + kt * 32);
  }
  asm volatile("s_waitcnt vmcnt(6)" ::: "memory");
  __builtin_amdgcn_s_barrier();
  __builtin_amdgcn_sched_barrier(0);

  for (int t = 0; t < NT; t++) {
    const u16* rb = smem + (t & 3) * 12288;
    u16* sb = smem + ((t + 3) & 3) * 12288;
    if (t + 3 < NT) {
      ld_lds16(sb + lds_u, gA0 + (t + 3) * 32);
      ld_lds16(sb + 4096 + lds_u, gB0 + (t + 3) * 32);
      ld_lds16(sb + 8192 + lds_u, gB1 + (t + 3) * 32);
    }
    s16x8 af[4], bfr[4];
#pragma unroll
    for (int f = 0; f < 4; f++)
      af[f] = *(const s16x8*)(rb + aoff + f * 512);
#pragma unroll
    for (int g = 0; g < 4; g++)
      bfr[g] = *(const s16x8*)(rb + 4096 + boff + g * 512);
    if (t < NT - 3) {
      asm volatile("s_waitcnt vmcnt(6)" ::: "memory");
    } else if (t == NT - 3) {
      asm volatile("s_waitcnt vmcnt(3)" ::: "memory");
    } else if (t == NT - 2) {
      asm volatile("s_waitcnt vmcnt(0)" ::: "memory");
    }
    __builtin_amdgcn_s_setprio(1);
#pragma unroll
    for (int f = 0; f < 4; f++)
#pragma unroll
      for (int g = 0; g < 4; g++)
        acc[f][g] = __builtin_amdgcn_mfma_f32_16x16x32_bf16(af[f], bfr[g], acc[f][g], 0, 0, 0);
    __builtin_amdgcn_s_setprio(0);
    __builtin_amdgcn_sched_barrier(0);
    __builtin_amdgcn_s_barrier();
    __builtin_amdgcn_sched_barrier(0);
  }
}

// ---------------- GEMM1: h_in = A1 @ W1'^T + b1; z->zbuf(f16), r*h->A2 ------
__global__ __launch_bounds__(512, 2) void gemm1_kernel(const u16* __restrict__ A1,
                                                       const u16* __restrict__ W1,
                                                       const float* __restrict__ b1,
                                                       _Float16* __restrict__ zbuf,
                                                       u16* __restrict__ A2) {
  __shared__ u16 smem[65536];
  const int bx = blockIdx.x;
  const int wg = (bx & 7) * 32 + (bx >> 3);  // XCD swizzle, 256 wgs
  const int m0 = (wg >> 2) << 8;
  const int n0 = (wg & 3) << 8;
  f32x4 acc[8][4];
  gemm_core8(A1, W1, m0, n0, smem, acc);

  const int lane = threadIdx.x & 63;
  const int wid = threadIdx.x >> 6;
  const int wm = wid >> 2;
  const int wn = wid & 3;
  const int fcol = lane & 15;
  const int frow = (lane >> 4) << 2;

  if (n0 < FDIM) {  // z-half
#pragma unroll
    for (int f = 0; f < 8; f++)
#pragma unroll
      for (int g = 0; g < 4; g++)
#pragma unroll
        for (int r = 0; r < 4; r++) {
          int gm = m0 + wm * 128 + f * 16 + frow + r;
          int gn = n0 + wn * 64 + g * 16 + fcol;
          float v = acc[f][g][r] + b1[gn];
          zbuf[(size_t)gm * FDIM + gn] = (_Float16)fast_sigmoid(v);
        }
  } else {  // r-half -> A2 left = bf16(r*h)
#pragma unroll
    for (int f = 0; f < 8; f++)
#pragma unroll
      for (int g = 0; g < 4; g++)
#pragma unroll
        for (int r = 0; r < 4; r++) {
          int gm = m0 + wm * 128 + f * 16 + frow + r;
          int gn = n0 + wn * 64 + g * 16 + fcol;
          float v = acc[f][g][r] + b1[gn];
          float s = fast_sigmoid(v);
          int c = gn - FDIM;
          float h = bf2f(A1[(size_t)gm * F2 + FDIM + c]);
          A2[(size_t)gm * F2 + c] = f2bf(s * h);
        }
  }
}

// ---------------- GEMM2: h_out = tanh(A2 @ W2^T + b2); gated update ---------
__global__ __launch_bounds__(512, 2) void gemm2_kernel(const u16* __restrict__ A2,
                                                       const u16* __restrict__ W2,
                                                       const float* __restrict__ b2,
                                                       const _Float16* __restrict__ zbuf,
                                                       u16* __restrict__ A1,
                                                       float* __restrict__ out,
                                                       int last) {
  __shared__ u16 smem[49152];
  const int bx = blockIdx.x;
  const int wg = (bx & 7) * 32 + (bx >> 3);  // XCD swizzle, 256 wgs
  const int m0 = (wg >> 1) << 7;             // BM=128
  const int n0 = (wg & 1) << 8;              // BN=256
  f32x4 acc[4][4];
  gemm_core4(A2, W2, m0, n0, smem, acc);

  const int lane = threadIdx.x & 63;
  const int wid = threadIdx.x >> 6;
  const int wm = wid >> 2;
  const int wn = wid & 3;
  const int fcol = lane & 15;
  const int frow = (lane >> 4) << 2;

#pragma unroll
  for (int f = 0; f < 4; f++)
#pragma unroll
    for (int g = 0; g < 4; g++)
#pragma unroll
      for (int r = 0; r < 4; r++) {
        int gm = m0 + wm * 64 + f * 16 + frow + r;
        int gn = n0 + wn * 64 + g * 16 + fcol;
        float v = acc[f][g][r] + b2[gn];
        float ho = fast_tanh(v);
        size_t idx = (size_t)gm * FDIM + gn;
        float z = (float)zbuf[idx];
        float hv = bf2f(A1[(size_t)gm * F2 + FDIM + gn]);
        float hn = (1.0f - z) * hv + z * ho;
        if (last)
          out[idx] = hn;
        else
          A1[(size_t)gm * F2 + FDIM + gn] = f2bf(hn);
      }
}

extern "C" void kernel_launch(void* const* d_in, const int* in_sizes, int n_in,
                              void* d_out, int out_size, void* d_ws, size_t ws_size,
                              hipStream_t stream) {
  (void)in_sizes; (void)n_in; (void)out_size; (void)ws_size;
  const float* x = (const float*)d_in[0];
  const float* masks = (const float*)d_in[1];
  const float* W1f = (const float*)d_in[2];
  const float* b1 = (const float*)d_in[3];
  const float* W2f = (const float*)d_in[4];
  const float* b2 = (const float*)d_in[5];

  char* ws = (char*)d_ws;
  float* fm = (float*)ws;       ws += (size_t)NST * FDIM * 4;
  u16* W1b = (u16*)ws;          ws += (size_t)NST * F2 * F2 * 2;
  u16* W2b = (u16*)ws;          ws += (size_t)NST * FDIM * F2 * 2;
  u16* A1 = (u16*)ws;           ws += (size_t)BATCH * F2 * 2;
  u16* A2 = (u16*)ws;           ws += (size_t)BATCH * F2 * 2;
  _Float16* zbuf = (_Float16*)ws; ws += (size_t)BATCH * FDIM * 2;
  float* out = (float*)d_out;

  entmax_kernel<<<NST, 512, 0, stream>>>(masks, fm);
  cvt_w1_kernel<<<NST * F2 * F2 / 4 / 256, 256, 0, stream>>>(W1f, fm, W1b);
  {
    int total = N4_W2 + BATCH * 128;  // W2 cvt + x-fill, one launch
    prep_kernel<<<(total + 255) / 256, 256, 0, stream>>>(W2f, W2b, x, A1, A2);
  }

  for (int d = 0; d < NST; d++) {
    gemm1_kernel<<<(BATCH / 256) * (F2 / 256), 512, 0, stream>>>(
        A1, W1b + (size_t)d * F2 * F2, b1 + d * F2, zbuf, A2);
    gemm2_kernel<<<(BATCH / 128) * (FDIM / 256), 512, 0, stream>>>(
        A2, W2b + (size_t)d * FDIM * F2, b2 + d * FDIM, zbuf,
        A1, out, d == NST - 1);
  }
}

// Round 18
// 479.002 us; speedup vs baseline: 1.0916x; 1.0312x over previous
//
#include <hip/hip_runtime.h>
#include <stdint.h>
#include <math.h>

typedef unsigned short u16;
typedef short s16x8 __attribute__((ext_vector_type(8)));
typedef float f32x4 __attribute__((ext_vector_type(4)));
typedef u16 u16x4 __attribute__((ext_vector_type(4)));

#define FDIM 512
#define F2 1024
#define BATCH 16384
#define NST 6
#define KDIM 1024
#define NT 32  // K-tiles of 32

// round-to-nearest-even fp32 -> bf16 bits
__device__ __forceinline__ u16 f2bf(float f) {
  uint32_t u = __float_as_uint(f);
  u += 0x7FFFu + ((u >> 16) & 1u);
  return (u16)(u >> 16);
}
__device__ __forceinline__ float bf2f(u16 b) {
  return __uint_as_float((uint32_t)b << 16);
}

// fast activations: v_exp_f32 + v_rcp_f32 (verified round 7: -65us, exact)
#define LOG2E 1.44269504f
__device__ __forceinline__ float fast_sigmoid(float v) {
  float e = __builtin_amdgcn_exp2f(-v * LOG2E);
  return __builtin_amdgcn_rcpf(1.0f + e);
}
__device__ __forceinline__ float fast_tanh(float v) {
  float e = __builtin_amdgcn_exp2f(v * (2.0f * LOG2E));
  return 1.0f - 2.0f * __builtin_amdgcn_rcpf(1.0f + e);
}

__device__ __forceinline__ void ld_lds16(u16* lds, const u16* g) {
  __builtin_amdgcn_global_load_lds(
      (const __attribute__((address_space(1))) uint32_t*)g,
      (__attribute__((address_space(3))) uint32_t*)lds, 16, 0, 0);
}

// ====== fused entmax (blocks 0..5) + prep (W2 cvt + x-fill, blocks 6+) ======
// entmax and prep are data-independent; only cvt_w1 (next launch, same
// stream) consumes fm, so the kernel boundary is the required barrier.
// Block-uniform branch -> no barrier-divergence hazard.
#define N4_W2 (NST * FDIM * F2 / 4)       // 786432 units (float4 of W2)
#define N_FILL (BATCH * 128)              // 2097152 units (float4 of x)
#define PREP_BLOCKS ((N4_W2 + N_FILL) / 512)  // 5632 exact

__global__ __launch_bounds__(512) void entmax_prep_kernel(
    const float* __restrict__ masks, float* __restrict__ fm,
    const float* __restrict__ W2f, u16* __restrict__ W2b,
    const float* __restrict__ x, u16* __restrict__ A1,
    u16* __restrict__ A2) {
  if (blockIdx.x < NST) {
    // ---- entmax 1.5, fully parallel (512 thr / row) — r5-verified body ----
    __shared__ float sx[FDIM];
    __shared__ float ssort[FDIM];
    __shared__ float stau[FDIM];
    __shared__ float2 sc[2][FDIM];
    const int d = blockIdx.x;
    const int j = threadIdx.x;
    float v = masks[d * FDIM + j];

    stau[j] = v;
    __syncthreads();
    for (int s = 256; s > 0; s >>= 1) {
      if (j < s) stau[j] = fmaxf(stau[j], stau[j + s]);
      __syncthreads();
    }
    float mx = stau[0];
    __syncthreads();

    float xx = (v - mx) * 0.5f;
    sx[j] = xx;
    __syncthreads();

    int r = 0;
    const float4* sx4 = (const float4*)sx;
#pragma unroll 4
    for (int i4 = 0; i4 < FDIM / 4; i4++) {
      float4 q = sx4[i4];
      int i = i4 << 2;
      r += (q.x > xx) || (q.x == xx && (i + 0) < j);
      r += (q.y > xx) || (q.y == xx && (i + 1) < j);
      r += (q.z > xx) || (q.z == xx && (i + 2) < j);
      r += (q.w > xx) || (q.w == xx && (i + 3) < j);
    }
    ssort[r] = xx;
    __syncthreads();
    float xs = ssort[j];

    // inclusive Hillis-Steele scan of (xs, xs^2)
    sc[0][j] = make_float2(xs, xs * xs);
    __syncthreads();
    int pp = 0;
    for (int off = 1; off < FDIM; off <<= 1) {
      float2 t = sc[pp][j];
      if (j >= off) {
        float2 u = sc[pp][j - off];
        t.x += u.x;
        t.y += u.y;
      }
      sc[pp ^ 1][j] = t;
      __syncthreads();
      pp ^= 1;
    }
    float2 cs = sc[pp][j];

    float rho = (float)(j + 1);
    float mean = cs.x / rho;
    float msq = cs.y / rho;
    float ss = rho * (msq - mean * mean);
    float delta = (1.f - ss) / rho;
    if (delta < 0.f) delta = 0.f;
    float tau = mean - sqrtf(delta);
    stau[j] = tau;
    int cnt = __syncthreads_count(tau <= xs);
    float tstar = stau[cnt - 1];
    float c = fmaxf(xx - tstar, 0.f);
    fm[d * FDIM + j] = c * c;
    return;
  }
  // ---- prep: W2 -> bf16 and A1/A2 x-fill (r12-verified bodies) ----
  int t = (blockIdx.x - NST) * 512 + threadIdx.x;
  if (t < N4_W2) {
    float4 v = *(const float4*)(W2f + (size_t)t * 4);
    u16x4 o = {f2bf(v.x), f2bf(v.y), f2bf(v.z), f2bf(v.w)};
    *(u16x4*)(W2b + (size_t)t * 4) = o;
  } else {
    int u = t - N4_W2;
    int m = u >> 7;
    int c = (u & 127) << 2;
    float4 xv = *(const float4*)(x + (size_t)m * FDIM + c);
    u16x4 o = {f2bf(xv.x), f2bf(xv.y), f2bf(xv.z), f2bf(xv.w)};
    *(u16x4*)(A1 + (size_t)m * F2 + c) = o;
    *(u16x4*)(A1 + (size_t)m * F2 + FDIM + c) = o;  // h = x at stage 0 (bf16)
    *(u16x4*)(A2 + (size_t)m * F2 + FDIM + c) = o;
  }
}

// ---------------- W1 -> bf16, fm folded into first 512 cols -----------------
__global__ __launch_bounds__(256) void cvt_w1_kernel(const float* __restrict__ src,
                                                     const float* __restrict__ fm,
                                                     u16* __restrict__ dst) {
  int t = blockIdx.x * 256 + threadIdx.x;
  int k = (t & 255) << 2;
  int dn = t >> 8;
  int d = dn >> 10;
  float4 v = *(const float4*)(src + (size_t)t * 4);
  if (k < FDIM) {
    float4 s = *(const float4*)(fm + (size_t)d * FDIM + k);
    v.x *= s.x; v.y *= s.y; v.z *= s.z; v.w *= s.w;
  }
  u16x4 o = {f2bf(v.x), f2bf(v.y), f2bf(v.z), f2bf(v.w)};
  *(u16x4*)(dst + (size_t)t * 4) = o;
}

// ====================== 256x256 single-barrier GEMM core =====================
// (r8/r12-verified best) 512 thr = 8 waves (2M x 4N); per wave 128x64 =
// acc[8][4]. Ring-4 LDS, lead-3 staging, vmcnt(8) steady / 4 / 0 tail. ONE
// barrier per K-tile; stage at t targets buf (t+3)&3 == (t-1)&3 (reads
// drained before the end-of-(t-1) barrier). Swizzle cg = kg ^ ((row>>1)&3):
// 0 conflicts (verified r6; 32x32 variant re-conflicts, r14 — keep 16x16).
__device__ __forceinline__ void gemm_core8(const u16* __restrict__ Ag,
                                           const u16* __restrict__ Bg,
                                           int m0, int n0, u16* smem,
                                           f32x4 acc[8][4]) {
  const int tid = threadIdx.x;
  const int lane = tid & 63;
  const int wid = tid >> 6;
  const int wm = wid >> 2;  // 0..1
  const int wn = wid & 3;   // 0..3

  const int rs = tid >> 2;                               // 0..127
  const int colsw = ((tid & 3) ^ ((rs >> 1) & 3)) << 3;  // pre-swizzled global col
  const u16* gA0 = Ag + (size_t)(m0 + rs) * KDIM + colsw;
  const u16* gA1 = gA0 + (size_t)128 * KDIM;
  const u16* gB0 = Bg + (size_t)(n0 + rs) * KDIM + colsw;
  const u16* gB1 = gB0 + (size_t)128 * KDIM;
  const int lds_u = tid * 8;

  const int fcs = ((lane >> 4) ^ ((lane >> 1) & 3)) << 3;  // swizzled frag col
  const int aoff = (wm * 128 + (lane & 15)) * 32 + fcs;
  const int boff = (wn * 64 + (lane & 15)) * 32 + fcs;

#pragma unroll
  for (int i = 0; i < 8; i++)
#pragma unroll
    for (int j = 0; j < 4; j++) acc[i][j] = (f32x4){0.f, 0.f, 0.f, 0.f};

#pragma unroll
  for (int kt = 0; kt < 3; kt++) {
    u16* rb = smem + kt * 16384;
    ld_lds16(rb + lds_u, gA0 + kt * 32);
    ld_lds16(rb + 4096 + lds_u, gA1 + kt * 32);
    ld_lds16(rb + 8192 + lds_u, gB0 + kt * 32);
    ld_lds16(rb + 12288 + lds_u, gB1 + kt * 32);
  }
  asm volatile("s_waitcnt vmcnt(8)" ::: "memory");  // K-tile 0 landed
  __builtin_amdgcn_s_barrier();
  __builtin_amdgcn_sched_barrier(0);

  for (int t = 0; t < NT; t++) {
    const u16* rb = smem + (t & 3) * 16384;
    u16* sb = smem + ((t + 3) & 3) * 16384;
    // issue next-tile stage first (flies during ds_reads + MFMA)
    if (t + 3 < NT) {
      ld_lds16(sb + lds_u, gA0 + (t + 3) * 32);
      ld_lds16(sb + 4096 + lds_u, gA1 + (t + 3) * 32);
      ld_lds16(sb + 8192 + lds_u, gB0 + (t + 3) * 32);
      ld_lds16(sb + 12288 + lds_u, gB1 + (t + 3) * 32);
    }
    // all 12 frags of this tile
    s16x8 af[8], bfr[4];
#pragma unroll
    for (int f = 0; f < 8; f++)
      af[f] = *(const s16x8*)(rb + aoff + f * 512);
#pragma unroll
    for (int g = 0; g < 4; g++)
      bfr[g] = *(const s16x8*)(rb + 8192 + boff + g * 512);
    // own buf[t+1] loads landed (8 = t+2,t+3 still in flight)
    if (t < NT - 3) {
      asm volatile("s_waitcnt vmcnt(8)" ::: "memory");
    } else if (t == NT - 3) {
      asm volatile("s_waitcnt vmcnt(4)" ::: "memory");
    } else if (t == NT - 2) {
      asm volatile("s_waitcnt vmcnt(0)" ::: "memory");
    }
    __builtin_amdgcn_s_setprio(1);
#pragma unroll
    for (int f = 0; f < 8; f++)
#pragma unroll
      for (int g = 0; g < 4; g++)
        acc[f][g] = __builtin_amdgcn_mfma_f32_16x16x32_bf16(af[f], bfr[g], acc[f][g], 0, 0, 0);
    __builtin_amdgcn_s_setprio(0);
    __builtin_amdgcn_sched_barrier(0);
    __builtin_amdgcn_s_barrier();  // single rendezvous per K-tile
    __builtin_amdgcn_sched_barrier(0);
  }
}

// ====================== 128x256 single-barrier GEMM core =====================
// per wave 64x64 = acc[4][4]. Ring-4 x 24KB, lead-3, vmcnt(6/3/0),
// 16 MFMA + 1 barrier per K-tile (same safety argument as core8).
__device__ __forceinline__ void gemm_core4(const u16* __restrict__ Ag,
                                           const u16* __restrict__ Bg,
                                           int m0, int n0, u16* smem,
                                           f32x4 acc[4][4]) {
  const int tid = threadIdx.x;
  const int lane = tid & 63;
  const int wid = tid >> 6;
  const int wm = wid >> 2;
  const int wn = wid & 3;

  const int rs = tid >> 2;
  const int colsw = ((tid & 3) ^ ((rs >> 1) & 3)) << 3;
  const u16* gA0 = Ag + (size_t)(m0 + rs) * KDIM + colsw;
  const u16* gB0 = Bg + (size_t)(n0 + rs) * KDIM + colsw;
  const u16* gB1 = gB0 + (size_t)128 * KDIM;
  const int lds_u = tid * 8;

  const int fcs = ((lane >> 4) ^ ((lane >> 1) & 3)) << 3;
  const int aoff = (wm * 64 + (lane & 15)) * 32 + fcs;
  const int boff = (wn * 64 + (lane & 15)) * 32 + fcs;

#pragma unroll
  for (int i = 0; i < 4; i++)
#pragma unroll
    for (int j = 0; j < 4; j++) acc[i][j] = (f32x4){0.f, 0.f, 0.f, 0.f};

#pragma unroll
  for (int kt = 0; kt < 3; kt++) {
    u16* rb = smem + kt * 12288;
    ld_lds16(rb + lds_u, gA0 + kt * 32);
    ld_lds16(rb + 4096 + lds_u, gB0 + kt * 32);
    ld_lds16(rb + 8192 + lds_u, gB1 + kt * 32);
  }
  asm volatile("s_waitcnt vmcnt(6)" ::: "memory");
  __builtin_amdgcn_s_barrier();
  __builtin_amdgcn_sched_barrier(0);

  for (int t = 0; t < NT; t++) {
    const u16* rb = smem + (t & 3) * 12288;
    u16* sb = smem + ((t + 3) & 3) * 12288;
    if (t + 3 < NT) {
      ld_lds16(sb + lds_u, gA0 + (t + 3) * 32);
      ld_lds16(sb + 4096 + lds_u, gB0 + (t + 3) * 32);
      ld_lds16(sb + 8192 + lds_u, gB1 + (t + 3) * 32);
    }
    s16x8 af[4], bfr[4];
#pragma unroll
    for (int f = 0; f < 4; f++)
      af[f] = *(const s16x8*)(rb + aoff + f * 512);
#pragma unroll
    for (int g = 0; g < 4; g++)
      bfr[g] = *(const s16x8*)(rb + 4096 + boff + g * 512);
    if (t < NT - 3) {
      asm volatile("s_waitcnt vmcnt(6)" ::: "memory");
    } else if (t == NT - 3) {
      asm volatile("s_waitcnt vmcnt(3)" ::: "memory");
    } else if (t == NT - 2) {
      asm volatile("s_waitcnt vmcnt(0)" ::: "memory");
    }
    __builtin_amdgcn_s_setprio(1);
#pragma unroll
    for (int f = 0; f < 4; f++)
#pragma unroll
      for (int g = 0; g < 4; g++)
        acc[f][g] = __builtin_amdgcn_mfma_f32_16x16x32_bf16(af[f], bfr[g], acc[f][g], 0, 0, 0);
    __builtin_amdgcn_s_setprio(0);
    __builtin_amdgcn_sched_barrier(0);
    __builtin_amdgcn_s_barrier();
    __builtin_amdgcn_sched_barrier(0);
  }
}

// ---------------- GEMM1: h_in = A1 @ W1'^T + b1; z->zbuf(f16), r*h->A2 ------
__global__ __launch_bounds__(512, 2) void gemm1_kernel(const u16* __restrict__ A1,
                                                       const u16* __restrict__ W1,
                                                       const float* __restrict__ b1,
                                                       _Float16* __restrict__ zbuf,
                                                       u16* __restrict__ A2) {
  __shared__ u16 smem[65536];
  const int bx = blockIdx.x;
  const int wg = (bx & 7) * 32 + (bx >> 3);  // XCD swizzle, 256 wgs
  const int m0 = (wg >> 2) << 8;
  const int n0 = (wg & 3) << 8;
  f32x4 acc[8][4];
  gemm_core8(A1, W1, m0, n0, smem, acc);

  const int lane = threadIdx.x & 63;
  const int wid = threadIdx.x >> 6;
  const int wm = wid >> 2;
  const int wn = wid & 3;
  const int fcol = lane & 15;
  const int frow = (lane >> 4) << 2;

  if (n0 < FDIM) {  // z-half
#pragma unroll
    for (int f = 0; f < 8; f++)
#pragma unroll
      for (int g = 0; g < 4; g++)
#pragma unroll
        for (int r = 0; r < 4; r++) {
          int gm = m0 + wm * 128 + f * 16 + frow + r;
          int gn = n0 + wn * 64 + g * 16 + fcol;
          float v = acc[f][g][r] + b1[gn];
          zbuf[(size_t)gm * FDIM + gn] = (_Float16)fast_sigmoid(v);
        }
  } else {  // r-half -> A2 left = bf16(r*h)
#pragma unroll
    for (int f = 0; f < 8; f++)
#pragma unroll
      for (int g = 0; g < 4; g++)
#pragma unroll
        for (int r = 0; r < 4; r++) {
          int gm = m0 + wm * 128 + f * 16 + frow + r;
          int gn = n0 + wn * 64 + g * 16 + fcol;
          float v = acc[f][g][r] + b1[gn];
          float s = fast_sigmoid(v);
          int c = gn - FDIM;
          float h = bf2f(A1[(size_t)gm * F2 + FDIM + c]);
          A2[(size_t)gm * F2 + c] = f2bf(s * h);
        }
  }
}

// ---------------- GEMM2: h_out = tanh(A2 @ W2^T + b2); gated update ---------
__global__ __launch_bounds__(512, 2) void gemm2_kernel(const u16* __restrict__ A2,
                                                       const u16* __restrict__ W2,
                                                       const float* __restrict__ b2,
                                                       const _Float16* __restrict__ zbuf,
                                                       u16* __restrict__ A1,
                                                       float* __restrict__ out,
                                                       int last) {
  __shared__ u16 smem[49152];
  const int bx = blockIdx.x;
  const int wg = (bx & 7) * 32 + (bx >> 3);  // XCD swizzle, 256 wgs
  const int m0 = (wg >> 1) << 7;             // BM=128
  const int n0 = (wg & 1) << 8;              // BN=256
  f32x4 acc[4][4];
  gemm_core4(A2, W2, m0, n0, smem, acc);

  const int lane = threadIdx.x & 63;
  const int wid = threadIdx.x >> 6;
  const int wm = wid >> 2;
  const int wn = wid & 3;
  const int fcol = lane & 15;
  const int frow = (lane >> 4) << 2;

#pragma unroll
  for (int f = 0; f < 4; f++)
#pragma unroll
    for (int g = 0; g < 4; g++)
#pragma unroll
      for (int r = 0; r < 4; r++) {
        int gm = m0 + wm * 64 + f * 16 + frow + r;
        int gn = n0 + wn * 64 + g * 16 + fcol;
        float v = acc[f][g][r] + b2[gn];
        float ho = fast_tanh(v);
        size_t idx = (size_t)gm * FDIM + gn;
        float z = (float)zbuf[idx];
        float hv = bf2f(A1[(size_t)gm * F2 + FDIM + gn]);
        float hn = (1.0f - z) * hv + z * ho;
        if (last)
          out[idx] = hn;
        else
          A1[(size_t)gm * F2 + FDIM + gn] = f2bf(hn);
      }
}

extern "C" void kernel_launch(void* const* d_in, const int* in_sizes, int n_in,
                              void* d_out, int out_size, void* d_ws, size_t ws_size,
                              hipStream_t stream) {
  (void)in_sizes; (void)n_in; (void)out_size; (void)ws_size;
  const float* x = (const float*)d_in[0];
  const float* masks = (const float*)d_in[1];
  const float* W1f = (const float*)d_in[2];
  const float* b1 = (const float*)d_in[3];
  const float* W2f = (const float*)d_in[4];
  const float* b2 = (const float*)d_in[5];

  char* ws = (char*)d_ws;
  float* fm = (float*)ws;       ws += (size_t)NST * FDIM * 4;
  u16* W1b = (u16*)ws;          ws += (size_t)NST * F2 * F2 * 2;
  u16* W2b = (u16*)ws;          ws += (size_t)NST * FDIM * F2 * 2;
  u16* A1 = (u16*)ws;           ws += (size_t)BATCH * F2 * 2;
  u16* A2 = (u16*)ws;           ws += (size_t)BATCH * F2 * 2;
  _Float16* zbuf = (_Float16*)ws; ws += (size_t)BATCH * FDIM * 2;
  float* out = (float*)d_out;

  // fused: entmax (blocks 0..5) runs concurrently with W2-cvt + x-fill
  entmax_prep_kernel<<<NST + PREP_BLOCKS, 512, 0, stream>>>(
      masks, fm, W2f, W2b, x, A1, A2);
  // cvt_w1 consumes fm — kernel boundary above is the barrier
  cvt_w1_kernel<<<NST * F2 * F2 / 4 / 256, 256, 0, stream>>>(W1f, fm, W1b);

  for (int d = 0; d < NST; d++) {
    gemm1_kernel<<<(BATCH / 256) * (F2 / 256), 512, 0, stream>>>(
        A1, W1b + (size_t)d * F2 * F2, b1 + d * F2, zbuf, A2);
    gemm2_kernel<<<(BATCH / 128) * (FDIM / 256), 512, 0, stream>>>(
        A2, W2b + (size_t)d * FDIM * F2, b2 + d * FDIM, zbuf,
        A1, out, d == NST - 1);
  }
}